// Round 1
// 889.597 us; speedup vs baseline: 2.0040x; 2.0040x over previous
//
#include <hip/hip_runtime.h>
#include <hip/hip_bf16.h>
#include <math.h>

// LatentGraphLearner: attn = softmax(top20-mask(h Wq^T Wk h^T / sqrt(D) + ps*prior, diag=-inf))
// N=8192, D=512, TOPK=20, fp32 in/out.
//
// Correctness strategy: REPLICATE the fp32 reference arithmetic bit-for-bit.
// Q32/K32 computed as k-ascending fmaf chains (matches CPU BLAS microkernel).
// Bulk logits via bf16 MFMA are ONLY a candidate pre-filter (noise ~3.3e-3;
// margin 0.20 = 60 sigma). Every candidate is re-scored with the replicated
// fp32 chain: fmaf over k ascending, fdiv_rn by f32(sqrt(512)), then
// fadd_rn(fmul_rn(ps, prior)). Top-20 ranked by (fp32 value DESC, index ASC).
//
// R1 change: k3 rewritten. Old: iterative 64-max extraction (~33 serial
// reduction+rescan+2-barrier iterations/row) with 32KB LDS row staging
// (occupancy-capped at 4 blocks/CU, VALUBusy 27%). New: row in 32 VGPRs,
// bisection threshold T with count(v>=T) in [20,48] (~6 block-sum iters),
// candidates = {v >= T - MARGIN} (superset of old set -> identical top-20),
// LDS-atomic compact, parallel re-score (up to 256 cands), rank-by-count
// selection instead of 20x butterfly sort. LDS 37888 -> ~6KB.

#define MARGIN 0.20f
#define RSQRT_D 0.04419417382415922f

typedef __attribute__((ext_vector_type(8))) short short8;
typedef __attribute__((ext_vector_type(4))) float f32x4;

__device__ __forceinline__ unsigned long long ordkey(float v, int j) {
  unsigned u = __float_as_uint(v);
  u = (u & 0x80000000u) ? ~u : (u | 0x80000000u);
  return ((unsigned long long)u << 32) | (unsigned)(8191 - j);
}

// ---- K1: Q = h @ Wq^T, K = h @ Wk^T; fp32 k-sequential fmaf chains (BLAS-replicating),
//          fp32 + bf16 outputs ----
__global__ __launch_bounds__(256) void k1_qk(const float* __restrict__ h,
                                             const float* __restrict__ Wq,
                                             const float* __restrict__ Wk,
                                             float* __restrict__ Q32,
                                             float* __restrict__ K32,
                                             __hip_bfloat16* __restrict__ Qb,
                                             __hip_bfloat16* __restrict__ Kb) {
  __shared__ float hs[64][17];
  __shared__ float wqs[64][17];
  __shared__ float wks[64][17];
  const int t = threadIdx.x;
  const int tx = t & 15, ty = t >> 4;
  const int i0 = blockIdx.y * 64, e0 = blockIdx.x * 64;
  const int r = t >> 2, c4 = (t & 3) * 4;
  float aq[4][4] = {};
  float ak[4][4] = {};
  for (int k0 = 0; k0 < 512; k0 += 16) {   // k strictly ascending
    __syncthreads();
    {
      const float4 hv = *(const float4*)&h[(size_t)(i0 + r) * 512 + k0 + c4];
      hs[r][c4 + 0] = hv.x; hs[r][c4 + 1] = hv.y; hs[r][c4 + 2] = hv.z; hs[r][c4 + 3] = hv.w;
      const float4 qv = *(const float4*)&Wq[(size_t)(e0 + r) * 512 + k0 + c4];
      wqs[r][c4 + 0] = qv.x; wqs[r][c4 + 1] = qv.y; wqs[r][c4 + 2] = qv.z; wqs[r][c4 + 3] = qv.w;
      const float4 kv = *(const float4*)&Wk[(size_t)(e0 + r) * 512 + k0 + c4];
      wks[r][c4 + 0] = kv.x; wks[r][c4 + 1] = kv.y; wks[r][c4 + 2] = kv.z; wks[r][c4 + 3] = kv.w;
    }
    __syncthreads();
#pragma unroll
    for (int dd = 0; dd < 16; dd++) {      // ascending within tile
      float hv[4], qv[4], kv[4];
#pragma unroll
      for (int a = 0; a < 4; a++) hv[a] = hs[ty * 4 + a][dd];
#pragma unroll
      for (int b = 0; b < 4; b++) { qv[b] = wqs[tx * 4 + b][dd]; kv[b] = wks[tx * 4 + b][dd]; }
#pragma unroll
      for (int a = 0; a < 4; a++)
#pragma unroll
        for (int b = 0; b < 4; b++) {
          aq[a][b] = fmaf(hv[a], qv[b], aq[a][b]);   // serial dep chain per output
          ak[a][b] = fmaf(hv[a], kv[b], ak[a][b]);
        }
    }
  }
#pragma unroll
  for (int a = 0; a < 4; a++)
#pragma unroll
    for (int b = 0; b < 4; b++) {
      const size_t gi = (size_t)(i0 + ty * 4 + a) * 512 + e0 + tx * 4 + b;
      Q32[gi] = aq[a][b];
      K32[gi] = ak[a][b];
      Qb[gi] = __float2bfloat16(aq[a][b]);
      Kb[gi] = __float2bfloat16(ak[a][b]);
    }
}

// ---- K2: filter logits = Qb @ Kb^T * RSQRT_D + ps*prior, diag=-inf (m97 structure) ----
__global__ __launch_bounds__(256) void k2_logits(const short* __restrict__ Qb,
                                                 const short* __restrict__ Kb,
                                                 const float* __restrict__ prior,
                                                 const float* __restrict__ psp,
                                                 float* __restrict__ out) {
  __shared__ short As[128 * 32];
  __shared__ short Bs[128 * 32];
  const int t = threadIdx.x;
  const int w = t >> 6, l = t & 63;
  const int wr = w >> 1, wc = w & 1;
  const int i0 = blockIdx.y * 128, j0 = blockIdx.x * 128;

  f32x4 acc[4][4];
#pragma unroll
  for (int a = 0; a < 4; a++)
#pragma unroll
    for (int b = 0; b < 4; b++) acc[a][b] = (f32x4){0.f, 0.f, 0.f, 0.f};

  const int rA = t >> 2;
  const int cA = (t & 3) * 8;
  const short* gA = Qb + (size_t)(i0 + rA) * 512 + cA;
  const short* gB = Kb + (size_t)(j0 + rA) * 512 + cA;
  char* lA = (char*)As + w * 1024;
  char* lB = (char*)Bs + w * 1024;

  for (int k0 = 0; k0 < 512; k0 += 32) {
    __syncthreads();
    __builtin_amdgcn_global_load_lds((__attribute__((address_space(1))) void*)(gA + k0),
                                     (__attribute__((address_space(3))) void*)(lA), 16, 0, 0);
    __builtin_amdgcn_global_load_lds((__attribute__((address_space(1))) void*)(gA + 64 * 512 + k0),
                                     (__attribute__((address_space(3))) void*)(lA + 4096), 16, 0, 0);
    __builtin_amdgcn_global_load_lds((__attribute__((address_space(1))) void*)(gB + k0),
                                     (__attribute__((address_space(3))) void*)(lB), 16, 0, 0);
    __builtin_amdgcn_global_load_lds((__attribute__((address_space(1))) void*)(gB + 64 * 512 + k0),
                                     (__attribute__((address_space(3))) void*)(lB + 4096), 16, 0, 0);
    __syncthreads();

    const int m = l & 15, kq = (l >> 4) * 8;
    short8 af[4], bfr[4];
#pragma unroll
    for (int f = 0; f < 4; f++) {
      af[f]  = *(const short8*)&As[(wr * 64 + f * 16 + m) * 32 + kq];
      bfr[f] = *(const short8*)&Bs[(wc * 64 + f * 16 + m) * 32 + kq];
    }
#pragma unroll
    for (int fr = 0; fr < 4; fr++)
#pragma unroll
      for (int fc = 0; fc < 4; fc++)
        acc[fr][fc] = __builtin_amdgcn_mfma_f32_16x16x32_bf16(af[fr], bfr[fc], acc[fr][fc], 0, 0, 0);
  }

  const float psv = psp[0];
  const int m = l & 15, q = l >> 4;
#pragma unroll
  for (int fr = 0; fr < 4; fr++) {
    const int grb = i0 + wr * 64 + fr * 16 + q * 4;
#pragma unroll
    for (int fc = 0; fc < 4; fc++) {
      const int gc = j0 + wc * 64 + fc * 16 + m;
#pragma unroll
      for (int r = 0; r < 4; r++) {
        const int gr = grb + r;
        const size_t off = (size_t)gr * 8192 + gc;
        float v = acc[fr][fc][r] * RSQRT_D + psv * prior[off];
        if (gr == gc) v = -__builtin_inff();
        out[off] = v;
      }
    }
  }
}

// ---- block-wide reduction helpers (leading barrier protects previous reuse) ----
__device__ __forceinline__ float blockmax_f(float v, float* sred, int t) {
#pragma unroll
  for (int off = 32; off > 0; off >>= 1) v = fmaxf(v, __shfl_down(v, off));
  __syncthreads();
  if ((t & 63) == 0) sred[t >> 6] = v;
  __syncthreads();
  return fmaxf(fmaxf(sred[0], sred[1]), fmaxf(sred[2], sred[3]));
}
__device__ __forceinline__ int blocksum_i(int v, int* sred, int t) {
#pragma unroll
  for (int off = 32; off > 0; off >>= 1) v += __shfl_down(v, off);
  __syncthreads();
  if ((t & 63) == 0) sred[t >> 6] = v;
  __syncthreads();
  return sred[0] + sred[1] + sred[2] + sred[3];
}

// ---- K3: bisection threshold-select + replicated-fp32 re-score + top-20 + softmax + scatter ----
__global__ __launch_bounds__(256) void k3_topk(float* out,
                                               const float* __restrict__ Q32,
                                               const float* __restrict__ K32,
                                               const float* __restrict__ prior,
                                               const float* __restrict__ psp) {
  const int row = blockIdx.x;
  const int t = threadIdx.x;
  __shared__ __align__(16) float qrow[512];
  __shared__ float fred[4];
  __shared__ int ired[4];
  __shared__ int candi[256];
  __shared__ unsigned long long keys[256];
  __shared__ int ncand_s;
  __shared__ float sel20v[20];
  __shared__ int sel20i[20];
  __shared__ double ex[20];
  __shared__ float wout[20];

  const float psv = psp[0];
  float* lrow = out + (size_t)row * 8192;

  // row into registers: 8 x float4 per thread, coalesced.
  // r[u*4+k] holds element j = 4*t + 1024*u + k.
  float r[32];
  {
    const float4* lr4 = (const float4*)lrow;
#pragma unroll
    for (int u = 0; u < 8; u++) {
      const float4 v = lr4[t + 256 * u];
      r[u * 4 + 0] = v.x; r[u * 4 + 1] = v.y; r[u * 4 + 2] = v.z; r[u * 4 + 3] = v.w;
    }
  }
  for (int e = t; e < 512; e += 256) qrow[e] = Q32[(size_t)row * 512 + e];
  if (t == 0) ncand_s = 0;

  float pm = r[0];
#pragma unroll
  for (int u = 1; u < 32; u++) pm = fmaxf(pm, r[u]);
  const float M = blockmax_f(pm, fred, t);

  // bisection: find T <= v'(20) with count(v' >= T) in [20,48] (early exit),
  // else largest verified T with count >= 20. Uniform control flow.
  float lo = M - 8.0f, hi = M;
  {
    int c = 0;
#pragma unroll
    for (int u = 0; u < 32; u++) c += (r[u] >= lo) ? 1 : 0;
    int ctot = blocksum_i(c, ired, t);
    float w = 8.0f;
    int guard = 0;
    while (ctot < 20 && guard < 140) {   // safety net; unreachable for this data
      w *= 2.0f; lo = M - w;
      c = 0;
#pragma unroll
      for (int u = 0; u < 32; u++) c += (r[u] >= lo) ? 1 : 0;
      ctot = blocksum_i(c, ired, t);
      guard++;
    }
  }
  float T = lo;
  for (int it = 0; it < 15; it++) {
    const float mid = 0.5f * (lo + hi);
    int c = 0;
#pragma unroll
    for (int u = 0; u < 32; u++) c += (r[u] >= mid) ? 1 : 0;
    const int ctot = blocksum_i(c, ired, t);
    if (ctot >= 20) {
      lo = mid; T = mid;
      if (ctot <= 48) break;
    } else {
      hi = mid;
    }
  }

  // compact candidates: all j with filter value >= T - MARGIN.
  // T <= v'(20) => this is a superset of {v' >= v'(20) - MARGIN}, which
  // (MARGIN >> 2*bf16-noise) contains the true fp32 top-20.
  const float Tc = T - MARGIN;
#pragma unroll
  for (int u2 = 0; u2 < 32; u2++) {
    if (r[u2] >= Tc) {
      const int p = atomicAdd(&ncand_s, 1);
      if (p < 256) candi[p] = 4 * t + 1024 * (u2 >> 2) + (u2 & 3);
    }
  }
  __syncthreads();
  const int ncand = min(ncand_s, 256);

  // replicated-fp32 re-score: k-sequential fmaf chain, then np's exact tail ops
  float Lf = -__builtin_inff();
  int myi = 0x7fffffff;
  unsigned long long mykey = 0ull;
  if (t < ncand) {
    myi = candi[t];
    const float* kr = &K32[(size_t)myi * 512];
    float s = 0.f;
#pragma unroll 8
    for (int k = 0; k < 512; k += 4) {
      const float4 kv = *(const float4*)&kr[k];
      s = fmaf(qrow[k + 0], kv.x, s);
      s = fmaf(qrow[k + 1], kv.y, s);
      s = fmaf(qrow[k + 2], kv.z, s);
      s = fmaf(qrow[k + 3], kv.w, s);
    }
    Lf = __fdiv_rn(s, 22.62741699796952f);                        // f32(math.sqrt(512))
    Lf = __fadd_rn(Lf, __fmul_rn(psv, prior[(size_t)row * 8192 + myi]));
    mykey = ordkey(Lf, myi);
  }
  keys[t] = mykey;
  __syncthreads();

  // rank-by-count: keys all-distinct (index tiebreak) => exactly 20 writers,
  // rank order == (fp32 value DESC, index ASC) == lax.top_k semantics.
  if (t < ncand) {
    int rank = 0;
    for (int jj = 0; jj < ncand; jj++) rank += (keys[jj] > mykey) ? 1 : 0;
    if (rank < 20) { sel20v[rank] = Lf; sel20i[rank] = myi; }
  }
  __syncthreads();

  // softmax over the 20 kept logits (fp64 internals; identical to passing version)
  if (t < 20) {
    float m2 = sel20v[0];
    for (int k = 1; k < 20; k++) m2 = fmaxf(m2, sel20v[k]);
    ex[t] = exp((double)sel20v[t] - (double)m2);
  }
  __syncthreads();
  if (t == 0) {
    double Z = 0.0;
    for (int k = 0; k < 20; k++) Z += ex[k];
    for (int k = 0; k < 20; k++) wout[k] = (float)(ex[k] / Z);
  }
  __syncthreads();

  const float4 z = {0.f, 0.f, 0.f, 0.f};
  for (int c = t; c < 2048; c += 256) ((float4*)lrow)[c] = z;
  __syncthreads();
  if (t < 20) lrow[sel20i[t]] = wout[t];
}

extern "C" void kernel_launch(void* const* d_in, const int* in_sizes, int n_in,
                              void* d_out, int out_size, void* d_ws, size_t ws_size,
                              hipStream_t stream) {
  const float* h     = (const float*)d_in[0];
  const float* prior = (const float*)d_in[1];
  const float* Wq    = (const float*)d_in[2];
  const float* Wk    = (const float*)d_in[3];
  const float* ps    = (const float*)d_in[4];
  float* out = (float*)d_out;

  char* ws = (char*)d_ws;
  float* Q32 = (float*)ws;                                         // 16 MB
  float* K32 = (float*)(ws + ((size_t)16 << 20));                  // 16 MB
  __hip_bfloat16* Qb = (__hip_bfloat16*)(ws + ((size_t)32 << 20)); //  8 MB
  __hip_bfloat16* Kb = (__hip_bfloat16*)(ws + ((size_t)40 << 20)); //  8 MB

  k1_qk<<<dim3(8, 128), 256, 0, stream>>>(h, Wq, Wk, Q32, K32, Qb, Kb);
  k2_logits<<<dim3(64, 64), 256, 0, stream>>>((const short*)Qb, (const short*)Kb,
                                              prior, ps, out);
  k3_topk<<<8192, 256, 0, stream>>>(out, Q32, K32, prior, ps);
}

// Round 3
// 811.695 us; speedup vs baseline: 2.1963x; 1.0960x over previous
//
#include <hip/hip_runtime.h>
#include <hip/hip_bf16.h>
#include <math.h>

// LatentGraphLearner: attn = softmax(top20-mask(h Wq^T Wk h^T / sqrt(D) + ps*prior, diag=-inf))
// N=8192, D=512, TOPK=20, fp32 in/out.
//
// Correctness strategy: REPLICATE the fp32 reference arithmetic bit-for-bit.
// Q32/K32 computed as k-ascending fmaf chains (matches CPU BLAS microkernel).
// Bulk logits (bf16 MFMA, stored bf16) are ONLY a candidate pre-filter: total
// filter error (MFMA ~3.3e-3 + bf16 store round ~0.016) << MARGIN/2 = 0.1.
// Every candidate is re-scored with the replicated fp32 chain: fmaf over k
// ascending, fdiv_rn by f32(sqrt(512)), then fadd_rn(fmul_rn(ps, prior)).
// Top-20 ranked by (fp32 value DESC, index ASC) = lax.top_k semantics.
//
// R3 = R2 resubmission (R2 bench failed on container infra, no counters).
// R2 changes under test:
//  - k1: 8x4 register blocking (tile 128x64), interleaved frag assignment
//    (rows ty+16a, cols tx+16b; pitch 20 floats), all LDS as b128. FMA order
//    per output UNCHANGED (k ascending, serial chain) => bit-identical Q/K.
//  - k2: filter stored bf16 into the FIRST 16KB of out row gr's own 32KB
//    region (no extra workspace; block r reads row r's filt before zeroing
//    row r => no cross-block hazard). Write 268->134 MB. + XCD swizzle.
//  - k3: reads bf16 filt (16KB/row), zeroes its own float4 slots right
//    after loading (overlaps the zero-write with bisection/re-score).

#define MARGIN 0.20f
#define RSQRT_D 0.04419417382415922f

typedef __attribute__((ext_vector_type(8))) short short8;
typedef __attribute__((ext_vector_type(8))) unsigned short ushort8;
typedef __attribute__((ext_vector_type(4))) float f32x4;

__device__ __forceinline__ unsigned long long ordkey(float v, int j) {
  unsigned u = __float_as_uint(v);
  u = (u & 0x80000000u) ? ~u : (u | 0x80000000u);
  return ((unsigned long long)u << 32) | (unsigned)(8191 - j);
}

// ---- K1: Q = h @ Wq^T, K = h @ Wk^T; fp32 k-sequential fmaf chains (BLAS-replicating),
//          fp32 + bf16 outputs. 8x4 blocking, b128 LDS traffic. ----
__global__ __launch_bounds__(256) void k1_qk(const float* __restrict__ h,
                                             const float* __restrict__ Wq,
                                             const float* __restrict__ Wk,
                                             float* __restrict__ Q32,
                                             float* __restrict__ K32,
                                             __hip_bfloat16* __restrict__ Qb,
                                             __hip_bfloat16* __restrict__ Kb) {
  __shared__ float hs[128][20];   // pitch 20 floats = 80B (16B aligned)
  __shared__ float wqs[64][20];
  __shared__ float wks[64][20];
  const int t = threadIdx.x;
  const int tx = t & 15, ty = t >> 4;
  const int i0 = blockIdx.y * 128, e0 = blockIdx.x * 64;
  const int r = t >> 2, c4 = (t & 3) * 4;
  float aq[8][4] = {};
  float ak[8][4] = {};
  for (int k0 = 0; k0 < 512; k0 += 16) {   // k strictly ascending
    __syncthreads();
    *(float4*)&hs[r][c4]      = *(const float4*)&h[(size_t)(i0 + r) * 512 + k0 + c4];
    *(float4*)&hs[64 + r][c4] = *(const float4*)&h[(size_t)(i0 + 64 + r) * 512 + k0 + c4];
    *(float4*)&wqs[r][c4]     = *(const float4*)&Wq[(size_t)(e0 + r) * 512 + k0 + c4];
    *(float4*)&wks[r][c4]     = *(const float4*)&Wk[(size_t)(e0 + r) * 512 + k0 + c4];
    __syncthreads();
#pragma unroll
    for (int d0 = 0; d0 < 16; d0 += 4) {
      f32x4 hv[8], qv[4], kv[4];
#pragma unroll
      for (int a = 0; a < 8; a++) hv[a] = *(const f32x4*)&hs[ty + 16 * a][d0];
#pragma unroll
      for (int b = 0; b < 4; b++) {
        qv[b] = *(const f32x4*)&wqs[tx + 16 * b][d0];
        kv[b] = *(const f32x4*)&wks[tx + 16 * b][d0];
      }
#pragma unroll
      for (int kk = 0; kk < 4; kk++)       // k = k0 + d0 + kk, strictly ascending
#pragma unroll
        for (int a = 0; a < 8; a++)
#pragma unroll
          for (int b = 0; b < 4; b++) {
            aq[a][b] = fmaf(hv[a][kk], qv[b][kk], aq[a][b]);   // serial chain per output
            ak[a][b] = fmaf(hv[a][kk], kv[b][kk], ak[a][b]);
          }
    }
  }
#pragma unroll
  for (int a = 0; a < 8; a++)
#pragma unroll
    for (int b = 0; b < 4; b++) {
      const size_t gi = (size_t)(i0 + ty + 16 * a) * 512 + e0 + tx + 16 * b;
      Q32[gi] = aq[a][b];
      K32[gi] = ak[a][b];
      Qb[gi] = __float2bfloat16(aq[a][b]);
      Kb[gi] = __float2bfloat16(ak[a][b]);
    }
}

// ---- K2: filter logits = Qb @ Kb^T * RSQRT_D + ps*prior, diag=-inf; bf16 store
//          into out row gr's first 16KB. m97 structure + XCD swizzle. ----
__global__ __launch_bounds__(256) void k2_logits(const short* __restrict__ Qb,
                                                 const short* __restrict__ Kb,
                                                 const float* __restrict__ prior,
                                                 const float* __restrict__ psp,
                                                 float* __restrict__ out) {
  __shared__ short As[128 * 32];
  __shared__ short Bs[128 * 32];
  const int t = threadIdx.x;
  const int w = t >> 6, l = t & 63;
  const int wr = w >> 1, wc = w & 1;
  // bijective XCD swizzle over 4096 blocks (4096 % 8 == 0)
  int flat = blockIdx.y * 64 + blockIdx.x;
  flat = (flat & 7) * 512 + (flat >> 3);
  const int i0 = (flat >> 6) * 128, j0 = (flat & 63) * 128;

  f32x4 acc[4][4];
#pragma unroll
  for (int a = 0; a < 4; a++)
#pragma unroll
    for (int b = 0; b < 4; b++) acc[a][b] = (f32x4){0.f, 0.f, 0.f, 0.f};

  const int rA = t >> 2;
  const int cA = (t & 3) * 8;
  const short* gA = Qb + (size_t)(i0 + rA) * 512 + cA;
  const short* gB = Kb + (size_t)(j0 + rA) * 512 + cA;
  char* lA = (char*)As + w * 1024;
  char* lB = (char*)Bs + w * 1024;

  for (int k0 = 0; k0 < 512; k0 += 32) {
    __syncthreads();
    __builtin_amdgcn_global_load_lds((__attribute__((address_space(1))) void*)(gA + k0),
                                     (__attribute__((address_space(3))) void*)(lA), 16, 0, 0);
    __builtin_amdgcn_global_load_lds((__attribute__((address_space(1))) void*)(gA + 64 * 512 + k0),
                                     (__attribute__((address_space(3))) void*)(lA + 4096), 16, 0, 0);
    __builtin_amdgcn_global_load_lds((__attribute__((address_space(1))) void*)(gB + k0),
                                     (__attribute__((address_space(3))) void*)(lB), 16, 0, 0);
    __builtin_amdgcn_global_load_lds((__attribute__((address_space(1))) void*)(gB + 64 * 512 + k0),
                                     (__attribute__((address_space(3))) void*)(lB + 4096), 16, 0, 0);
    __syncthreads();

    const int m = l & 15, kq = (l >> 4) * 8;
    short8 af[4], bfr[4];
#pragma unroll
    for (int f = 0; f < 4; f++) {
      af[f]  = *(const short8*)&As[(wr * 64 + f * 16 + m) * 32 + kq];
      bfr[f] = *(const short8*)&Bs[(wc * 64 + f * 16 + m) * 32 + kq];
    }
#pragma unroll
    for (int fr = 0; fr < 4; fr++)
#pragma unroll
      for (int fc = 0; fc < 4; fc++)
        acc[fr][fc] = __builtin_amdgcn_mfma_f32_16x16x32_bf16(af[fr], bfr[fc], acc[fr][fc], 0, 0, 0);
  }

  const float psv = psp[0];
  const int m = l & 15, q = l >> 4;
#pragma unroll
  for (int fr = 0; fr < 4; fr++) {
    const int grb = i0 + wr * 64 + fr * 16 + q * 4;
#pragma unroll
    for (int fc = 0; fc < 4; fc++) {
      const int gc = j0 + wc * 64 + fc * 16 + m;
#pragma unroll
      for (int rr = 0; rr < 4; rr++) {
        const int gr = grb + rr;
        const size_t off = (size_t)gr * 8192 + gc;
        float v = acc[fr][fc][rr] * RSQRT_D + psv * prior[off];
        if (gr == gc) v = -__builtin_inff();
        // bf16 filt for row gr lives in the first 16KB of out row gr (32KB)
        ((__hip_bfloat16*)(out + (size_t)gr * 8192))[gc] = __float2bfloat16(v);
      }
    }
  }
}

// ---- block-wide reduction helpers (leading barrier protects previous reuse) ----
__device__ __forceinline__ float blockmax_f(float v, float* sred, int t) {
#pragma unroll
  for (int off = 32; off > 0; off >>= 1) v = fmaxf(v, __shfl_down(v, off));
  __syncthreads();
  if ((t & 63) == 0) sred[t >> 6] = v;
  __syncthreads();
  return fmaxf(fmaxf(sred[0], sred[1]), fmaxf(sred[2], sred[3]));
}
__device__ __forceinline__ int blocksum_i(int v, int* sred, int t) {
#pragma unroll
  for (int off = 32; off > 0; off >>= 1) v += __shfl_down(v, off);
  __syncthreads();
  if ((t & 63) == 0) sred[t >> 6] = v;
  __syncthreads();
  return sred[0] + sred[1] + sred[2] + sred[3];
}

// ---- K3: bf16-filt bisection select + replicated-fp32 re-score + top-20 + softmax + scatter ----
__global__ __launch_bounds__(256) void k3_topk(float* out,
                                               const float* __restrict__ Q32,
                                               const float* __restrict__ K32,
                                               const float* __restrict__ prior,
                                               const float* __restrict__ psp) {
  const int row = blockIdx.x;
  const int t = threadIdx.x;
  __shared__ __align__(16) float qrow[512];
  __shared__ float fred[4];
  __shared__ int ired[4];
  __shared__ int candi[256];
  __shared__ unsigned long long keys[256];
  __shared__ int ncand_s;
  __shared__ float sel20v[20];
  __shared__ int sel20i[20];
  __shared__ double ex[20];
  __shared__ float wout[20];

  const float psv = psp[0];
  float* lrow = out + (size_t)row * 8192;

  // load bf16 filt (first 16KB of this row) into regs: 4 x float4 per thread
  float4 fv[4];
  {
    const float4* lr4 = (const float4*)lrow;
#pragma unroll
    for (int u = 0; u < 4; u++) fv[u] = lr4[t + 256 * u];
  }
  // early zero of THIS thread's own float4 slots (includes the filt slots it
  // just read; per-thread program order keeps load-before-store). Overlaps
  // the big write with the latency-bound selection phases below.
  {
    const float4 z = {0.f, 0.f, 0.f, 0.f};
#pragma unroll
    for (int u = 0; u < 8; u++) ((float4*)lrow)[t + 256 * u] = z;
  }
  // decode 32 bf16 values; r[u*8+e] holds filt for column j = 8t + 2048u + e
  float r[32];
#pragma unroll
  for (int u = 0; u < 4; u++) {
    const ushort8 us = *(const ushort8*)&fv[u];
#pragma unroll
    for (int e = 0; e < 8; e++)
      r[u * 8 + e] = __uint_as_float(((unsigned)us[e]) << 16);
  }
  for (int e = t; e < 512; e += 256) qrow[e] = Q32[(size_t)row * 512 + e];
  if (t == 0) ncand_s = 0;

  float pm = r[0];
#pragma unroll
  for (int u = 1; u < 32; u++) pm = fmaxf(pm, r[u]);
  const float M = blockmax_f(pm, fred, t);

  // bisection: find T <= v'(20) with count(v' >= T) in [20,48] (early exit),
  // else largest verified T with count >= 20. Uniform control flow.
  float lo = M - 8.0f, hi = M;
  {
    int c = 0;
#pragma unroll
    for (int u = 0; u < 32; u++) c += (r[u] >= lo) ? 1 : 0;
    int ctot = blocksum_i(c, ired, t);
    float w = 8.0f;
    int guard = 0;
    while (ctot < 20 && guard < 140) {   // safety net; unreachable for this data
      w *= 2.0f; lo = M - w;
      c = 0;
#pragma unroll
      for (int u = 0; u < 32; u++) c += (r[u] >= lo) ? 1 : 0;
      ctot = blocksum_i(c, ired, t);
      guard++;
    }
  }
  float T = lo;
  for (int it = 0; it < 15; it++) {
    const float mid = 0.5f * (lo + hi);
    int c = 0;
#pragma unroll
    for (int u = 0; u < 32; u++) c += (r[u] >= mid) ? 1 : 0;
    const int ctot = blocksum_i(c, ired, t);
    if (ctot >= 20) {
      lo = mid; T = mid;
      if (ctot <= 48) break;
    } else {
      hi = mid;
    }
  }

  // compact candidates: all j with filt >= T - MARGIN. T <= filt'(20) =>
  // superset of {filt >= filt'(20) - MARGIN}; filter error (MFMA + bf16
  // rounding) ~0.016 << MARGIN/2 => contains the true fp32 top-20.
  const float Tc = T - MARGIN;
#pragma unroll
  for (int u2 = 0; u2 < 32; u2++) {
    if (r[u2] >= Tc) {
      const int p = atomicAdd(&ncand_s, 1);
      if (p < 256) candi[p] = 8 * t + 2048 * (u2 >> 3) + (u2 & 7);
    }
  }
  __syncthreads();
  const int ncand = min(ncand_s, 256);

  // replicated-fp32 re-score: k-sequential fmaf chain, then np's exact tail ops
  float Lf = -__builtin_inff();
  int myi = 0x7fffffff;
  unsigned long long mykey = 0ull;
  if (t < ncand) {
    myi = candi[t];
    const float* kr = &K32[(size_t)myi * 512];
    float s = 0.f;
#pragma unroll 8
    for (int k = 0; k < 512; k += 4) {
      const float4 kv = *(const float4*)&kr[k];
      s = fmaf(qrow[k + 0], kv.x, s);
      s = fmaf(qrow[k + 1], kv.y, s);
      s = fmaf(qrow[k + 2], kv.z, s);
      s = fmaf(qrow[k + 3], kv.w, s);
    }
    Lf = __fdiv_rn(s, 22.62741699796952f);                        // f32(math.sqrt(512))
    Lf = __fadd_rn(Lf, __fmul_rn(psv, prior[(size_t)row * 8192 + myi]));
    mykey = ordkey(Lf, myi);
  }
  keys[t] = mykey;
  __syncthreads();

  // rank-by-count: keys all-distinct (index tiebreak) => exactly 20 writers,
  // rank order == (fp32 value DESC, index ASC) == lax.top_k semantics.
  if (t < ncand) {
    int rank = 0;
    for (int jj = 0; jj < ncand; jj++) rank += (keys[jj] > mykey) ? 1 : 0;
    if (rank < 20) { sel20v[rank] = Lf; sel20i[rank] = myi; }
  }
  __syncthreads();

  // softmax over the 20 kept logits (fp64 internals; identical to passing version)
  if (t < 20) {
    float m2 = sel20v[0];
    for (int k = 1; k < 20; k++) m2 = fmaxf(m2, sel20v[k]);
    ex[t] = exp((double)sel20v[t] - (double)m2);
  }
  __syncthreads();
  if (t == 0) {
    double Z = 0.0;
    for (int k = 0; k < 20; k++) Z += ex[k];
    for (int k = 0; k < 20; k++) wout[k] = (float)(ex[k] / Z);
  }
  __syncthreads();
  // zeros were written early (each thread zeroed its own slots, barriers since)
  if (t < 20) lrow[sel20i[t]] = wout[t];
}

extern "C" void kernel_launch(void* const* d_in, const int* in_sizes, int n_in,
                              void* d_out, int out_size, void* d_ws, size_t ws_size,
                              hipStream_t stream) {
  const float* h     = (const float*)d_in[0];
  const float* prior = (const float*)d_in[1];
  const float* Wq    = (const float*)d_in[2];
  const float* Wk    = (const float*)d_in[3];
  const float* ps    = (const float*)d_in[4];
  float* out = (float*)d_out;

  char* ws = (char*)d_ws;
  float* Q32 = (float*)ws;                                         // 16 MB
  float* K32 = (float*)(ws + ((size_t)16 << 20));                  // 16 MB
  __hip_bfloat16* Qb = (__hip_bfloat16*)(ws + ((size_t)32 << 20)); //  8 MB
  __hip_bfloat16* Kb = (__hip_bfloat16*)(ws + ((size_t)40 << 20)); //  8 MB

  k1_qk<<<dim3(8, 64), 256, 0, stream>>>(h, Wq, Wk, Q32, K32, Qb, Kb);
  k2_logits<<<dim3(64, 64), 256, 0, stream>>>((const short*)Qb, (const short*)Kb,
                                              prior, ps, out);
  k3_topk<<<8192, 256, 0, stream>>>(out, Q32, K32, prior, ps);
}